// Round 6
// baseline (322.142 us; speedup 1.0000x reference)
//
#include <hip/hip_runtime.h>
#include <hip/hip_bf16.h>
#include <cstdint>
#include <cstddef>

#define S_LEN   4096
#define BATCHN  4
#define DMODEL  1024
#define NHEADS  16
#define HDIM    64
#define MROWS   (S_LEN*BATCHN)   // 16384
#define NQKV    3072
#define KDIM    1024
#define KSPLIT  8
#define TP_PAD  66

typedef __bf16 bf16;
typedef bf16 bf16x8 __attribute__((ext_vector_type(8)));
typedef bf16 bf16x4 __attribute__((ext_vector_type(4)));
typedef float f32x4 __attribute__((ext_vector_type(4)));

#define MFMA16(a,b,c) __builtin_amdgcn_mfma_f32_16x16x32_bf16(a,b,c,0,0,0)

__device__ __forceinline__ void gll16(const void* g, void* l) {
  __builtin_amdgcn_global_load_lds((const __attribute__((address_space(1))) unsigned*)g,
                                   (__attribute__((address_space(3))) unsigned*)l,
                                   16, 0, 0);
}

// ---------------- cast fp32 -> bf16: h then x into contiguous hbf|xbf ----------------
__global__ __launch_bounds__(256) void cast_hx(const float* __restrict__ h,
                                               const float* __restrict__ x,
                                               bf16* __restrict__ dst) {
  const int n = 2 * MROWS * KDIM;          // 33,554,432 elements
  int stride = gridDim.x * blockDim.x * 4;
  for (int i = (blockIdx.x * blockDim.x + threadIdx.x) * 4; i < n; i += stride) {
    const float* src = (i < MROWS*KDIM) ? (h + i) : (x + i - MROWS*KDIM);
    float4 f = *(const float4*)src;
    bf16x4 o; o[0]=(bf16)f.x; o[1]=(bf16)f.y; o[2]=(bf16)f.z; o[3]=(bf16)f.w;
    *(bf16x4*)(dst + i) = o;
  }
}

// all four weight matrices -> contiguous wcat(3M) | wob(1M)
__global__ __launch_bounds__(256) void cast_w(const float* __restrict__ Wq,
                                              const float* __restrict__ Wk,
                                              const float* __restrict__ Wv,
                                              const float* __restrict__ Wo,
                                              bf16* __restrict__ dst) {
  const int n = 4 * 1048576;
  int stride = gridDim.x * blockDim.x * 4;
  for (int i = (blockIdx.x * blockDim.x + threadIdx.x) * 4; i < n; i += stride) {
    int r = i >> 20;
    const float* src = (r < 1) ? (Wq + i) : (r < 2) ? (Wk + i - 1048576)
                     : (r < 3) ? (Wv + i - 2097152) : (Wo + i - 3145728);
    float4 f = *(const float4*)src;
    bf16x4 o; o[0]=(bf16)f.x; o[1]=(bf16)f.y; o[2]=(bf16)f.z; o[3]=(bf16)f.w;
    *(bf16x4*)(dst + i) = o;
  }
}

// ---------------- GEMM C = A * B^T (+bias, +act), m97 structure + XOR bank swizzle ----
// LDS tiles [128 rows][64 B]; physical byte within row = logical ^ (((row>>1)&3)<<4).
// Store side pre-swizzles the GLOBAL source chunk (gll16 dest linear, rule #21);
// read side applies the same XOR. Fragment reads: rows 0..7 cover all 32 banks ->
// 2 lanes/bank (free). Pure involution => bit-identical results.
template<int MODE>
__global__ __launch_bounds__(256) void gemm_bt(
    const bf16* __restrict__ Ah, const bf16* __restrict__ Ax,
    const bf16* __restrict__ Bw,
    const float* __restrict__ b0, const float* __restrict__ b1,
    const float* __restrict__ b2,
    void* __restrict__ Cout) {
  __shared__ __align__(16) bf16 As[128*32];
  __shared__ __align__(16) bf16 Bs[128*32];
  const int tid  = threadIdx.x;
  const int wid  = tid >> 6;
  const int lane = tid & 63;
  const int wm = wid >> 1, wn = wid & 1;
  const int mtile = blockIdx.x, ntile = blockIdx.y;
  const bf16* Ap = (MODE == 0) ? (ntile < 8 ? Ah : Ax) : Ah;
  const size_t arow0 = (size_t)mtile * 128;
  const size_t brow0 = (size_t)ntile * 128;
  f32x4 acc[4][4] = {};
  const int lr = lane >> 2;        // row within 16-row segment
  const int lc = lane & 3;         // 16B chunk within row
  // source element offset within the 32-elem K-slab (pre-swizzled)
  const int ssrc = (((lc << 4) ^ (((lr >> 1) & 3) << 4)) >> 1);
  // fragment byte offsets
  const int fhalf = (lane >> 4) << 4;   // logical byte: 0,16,32,48

  for (int k0 = 0; k0 < KDIM; k0 += 32) {
    #pragma unroll
    for (int i = 0; i < 2; ++i) {
      int seg = (wid << 1) | i;    // 0..7
      gll16(Ap + (arow0 + seg*16 + lr) * KDIM + k0 + ssrc, As + seg*512);
      gll16(Bw + (brow0 + seg*16 + lr) * KDIM + k0 + ssrc, Bs + seg*512);
    }
    __syncthreads();
    bf16x8 af[4], bfv[4];
    #pragma unroll
    for (int m = 0; m < 4; ++m) {
      int R = wm*64 + m*16 + (lane & 15);
      af[m] = *(const bf16x8*)((const char*)As + R*64 + (fhalf ^ (((R >> 1) & 3) << 4)));
    }
    #pragma unroll
    for (int n = 0; n < 4; ++n) {
      int R = wn*64 + n*16 + (lane & 15);
      bfv[n] = *(const bf16x8*)((const char*)Bs + R*64 + (fhalf ^ (((R >> 1) & 3) << 4)));
    }
    #pragma unroll
    for (int m = 0; m < 4; ++m)
      #pragma unroll
      for (int n = 0; n < 4; ++n)
        acc[m][n] = MFMA16(af[m], bfv[n], acc[m][n]);
    __syncthreads();
  }

  #pragma unroll
  for (int m = 0; m < 4; ++m) {
    int rowb = mtile*128 + wm*64 + m*16 + ((lane >> 4) << 2);
    #pragma unroll
    for (int n = 0; n < 4; ++n) {
      int col = ntile*128 + wn*64 + n*16 + (lane & 15);
      if (MODE == 0) {
        float bias = (col < 1024) ? b0[col] : (col < 2048) ? b1[col-1024] : b2[col-2048];
        bf16* C = (bf16*)Cout;
        #pragma unroll
        for (int i = 0; i < 4; ++i) {
          float v = acc[m][n][i] + bias;
          if (col < 2048) v = (v > 0.f) ? v + 1.f : __expf(v);  // elu(x)+1
          C[(size_t)(rowb+i)*NQKV + col] = (bf16)v;
        }
      } else {
        float bias = b0[col];
        float* C = (float*)Cout;
        #pragma unroll
        for (int i = 0; i < 4; ++i)
          C[(size_t)(rowb+i)*DMODEL + col] = acc[m][n][i] + bias;
      }
    }
  }
}

// ---------------- transpose K,V halves of qkv into [bh][d][s]; Ksum partials ----------------
__global__ __launch_bounds__(256) void transpose_kv(const bf16* __restrict__ QKV,
                                                    bf16* __restrict__ Kt,
                                                    bf16* __restrict__ Vt,
                                                    float* __restrict__ Ksumg) {
  const int bh = blockIdx.x;
  const int sc0 = blockIdx.y * 128;
  const int b = bh >> 4, hh = bh & 15;
  const int tid = threadIdx.x;
  __shared__ bf16 Kl[128*TP_PAD];
  __shared__ bf16 Vl[128*TP_PAD];
  __shared__ float red[256];

  const int c = tid & 7;
  #pragma unroll
  for (int i = 0; i < 4; ++i) {
    int sr = (tid >> 3) + i * 32;
    size_t gaddr = ((size_t)(sc0 + sr) * BATCHN + b) * NQKV + 1024 + hh*64 + c*8;
    bf16x8 kv = *(const bf16x8*)(QKV + gaddr);
    bf16x8 vv = *(const bf16x8*)(QKV + gaddr + 1024);
    *(bf16x8*)(Kl + sr*TP_PAD + c*8) = kv;
    *(bf16x8*)(Vl + sr*TP_PAD + c*8) = vv;
  }
  __syncthreads();

  const int d = tid & 63;
  float ks = 0.f;
  #pragma unroll
  for (int i = 0; i < 4; ++i) {
    int sc = (tid >> 6) + i * 4;
    bf16x8 ko, vo;
    #pragma unroll
    for (int j = 0; j < 8; ++j) {
      bf16 kvv = Kl[(sc*8 + j)*TP_PAD + d];
      ko[j] = kvv;
      ks += (float)kvv;
      vo[j] = Vl[(sc*8 + j)*TP_PAD + d];
    }
    size_t obase = (size_t)bh * 64 * S_LEN + (size_t)d * S_LEN + sc0 + sc*8;
    *(bf16x8*)(Kt + obase) = ko;
    *(bf16x8*)(Vt + obase) = vo;
  }
  red[tid] = ks;
  __syncthreads();
  if (tid < 64) {
    float s = red[tid] + red[tid+64] + red[tid+128] + red[tid+192];
    atomicAdd(&Ksumg[bh*64 + tid], s);
  }
}

// ---------------- KV[bh][d][v] = sum_s Kt[bh][d][s] * Vt[bh][v][s], split-K ----------------
__global__ __launch_bounds__(256) void kv_gemm(const bf16* __restrict__ Kt,
                                               const bf16* __restrict__ Vt,
                                               float* __restrict__ KVg) {
  const int bh = blockIdx.x;
  const int k0base = blockIdx.y * (S_LEN / KSPLIT);
  const int tid = threadIdx.x, wid = tid >> 6, lane = tid & 63;
  const int wm = wid >> 1, wn = wid & 1;
  __shared__ __align__(16) bf16 Ks[64*64];
  __shared__ __align__(16) bf16 Vs[64*64];
  const bf16* Kh = Kt + (size_t)bh * 64 * S_LEN;
  const bf16* Vh = Vt + (size_t)bh * 64 * S_LEN;
  f32x4 acc[2][2] = {};

  for (int k0 = k0base; k0 < k0base + S_LEN/KSPLIT; k0 += 64) {
    #pragma unroll
    for (int j = 0; j < 4; ++j) {
      int cchunk = wid*4 + j;
      int r = (cchunk & 7) * 8 + (lane >> 3);
      int colb = (lane & 7) * 16;
      int scol = colb ^ ((r & 7) << 4);
      const bf16* src = (cchunk < 8) ? Kh : Vh;
      bf16* dst = ((cchunk < 8) ? Ks : Vs) + (size_t)(cchunk & 7) * 8 * 64;
      gll16(src + (size_t)r * S_LEN + k0 + (scol >> 1), dst);
    }
    __syncthreads();
    #pragma unroll
    for (int ksb = 0; ksb < 2; ++ksb) {
      bf16x8 af[2], bv[2];
      #pragma unroll
      for (int m = 0; m < 2; ++m) {
        int R = wm*32 + m*16 + (lane & 15);
        int cb = (ksb*64 + ((lane >> 4) << 4)) ^ ((R & 7) << 4);
        af[m] = *(const bf16x8*)((const char*)Ks + R*128 + cb);
      }
      #pragma unroll
      for (int n = 0; n < 2; ++n) {
        int R = wn*32 + n*16 + (lane & 15);
        int cb = (ksb*64 + ((lane >> 4) << 4)) ^ ((R & 7) << 4);
        bv[n] = *(const bf16x8*)((const char*)Vs + R*128 + cb);
      }
      #pragma unroll
      for (int m = 0; m < 2; ++m)
        #pragma unroll
        for (int n = 0; n < 2; ++n)
          acc[m][n] = MFMA16(af[m], bv[n], acc[m][n]);
    }
    __syncthreads();
  }

  #pragma unroll
  for (int m = 0; m < 2; ++m)
    #pragma unroll
    for (int n = 0; n < 2; ++n)
      #pragma unroll
      for (int i = 0; i < 4; ++i) {
        int dd = wm*32 + m*16 + ((lane >> 4) << 2) + i;
        int vv = wn*32 + n*16 + (lane & 15);
        atomicAdd(&KVg[(size_t)bh*4096 + dd*64 + vv], acc[m][n][i]);
      }
}

// ---------------- out_pre = (Qp @ KV) / Z ----------------
__global__ __launch_bounds__(256) void attn_out(const bf16* __restrict__ QKV,
                                                const float* __restrict__ KVg,
                                                const float* __restrict__ Ksumg,
                                                bf16* __restrict__ OP) {
  const int head = blockIdx.x, stile = blockIdx.y;
  const int b = head >> 4, hh = head & 15;
  const int tid = threadIdx.x;
  const int wid = tid >> 6, lane = tid & 63;
  const int s0 = stile * 128;
  __shared__ __align__(16) bf16 Qs[128*64];
  __shared__ __align__(16) bf16 KVt[64*64];
  __shared__ float ksum_s[64];
  __shared__ float rZ[128];

  const float* KVh = KVg + (size_t)head*4096;
  #pragma unroll
  for (int i = 0; i < 16; ++i) {
    int idx = i*256 + tid;
    int dd = idx >> 6, vv = idx & 63;
    KVt[vv*64 + dd] = (bf16)KVh[idx];
  }
  if (tid < 64) ksum_s[tid] = Ksumg[head*64 + tid];
  #pragma unroll
  for (int p = 0; p < 4; ++p) {
    int row = p*32 + wid*8 + (lane >> 3);
    gll16(QKV + ((size_t)(s0+row)*BATCHN + b)*NQKV + hh*64 + ((lane&7)<<3),
          Qs + (p*32 + wid*8)*64);
  }
  __syncthreads();

  if (tid < 128) {
    float z = 0.f;
    #pragma unroll
    for (int dd = 0; dd < 64; ++dd) z += (float)Qs[tid*64 + dd] * ksum_s[dd];
    rZ[tid] = 1.f / (z + 1e-6f);
  }
  __syncthreads();

  f32x4 acc[2][4] = {};
  #pragma unroll
  for (int ksb = 0; ksb < 2; ++ksb) {
    bf16x8 af[2], bv[4];
    #pragma unroll
    for (int m = 0; m < 2; ++m)
      af[m] = *(const bf16x8*)(Qs + (wid*32 + m*16 + (lane & 15))*64 + ksb*32 + ((lane>>4)<<3));
    #pragma unroll
    for (int n = 0; n < 4; ++n)
      bv[n] = *(const bf16x8*)(KVt + (n*16 + (lane & 15))*64 + ksb*32 + ((lane>>4)<<3));
    #pragma unroll
    for (int m = 0; m < 2; ++m)
      #pragma unroll
      for (int n = 0; n < 4; ++n)
        acc[m][n] = MFMA16(af[m], bv[n], acc[m][n]);
  }

  #pragma unroll
  for (int m = 0; m < 2; ++m)
    #pragma unroll
    for (int n = 0; n < 4; ++n)
      #pragma unroll
      for (int i = 0; i < 4; ++i) {
        int row = wid*32 + m*16 + ((lane >> 4) << 2) + i;
        int vv  = n*16 + (lane & 15);
        float val = acc[m][n][i] * rZ[row];
        OP[((size_t)(s0+row)*BATCHN + b)*DMODEL + hh*64 + vv] = (bf16)val;
      }
}

// ---------------- launch ----------------
extern "C" void kernel_launch(void* const* d_in, const int* in_sizes, int n_in,
                              void* d_out, int out_size, void* d_ws, size_t ws_size,
                              hipStream_t stream) {
  const float* h  = (const float*)d_in[0];
  const float* x  = (const float*)d_in[1];
  const float* Wq = (const float*)d_in[2];
  const float* bq = (const float*)d_in[3];
  const float* Wk = (const float*)d_in[4];
  const float* bk = (const float*)d_in[5];
  const float* Wv = (const float*)d_in[6];
  const float* bv = (const float*)d_in[7];
  const float* Wo = (const float*)d_in[8];
  const float* bo = (const float*)d_in[9];

  char* ws = (char*)d_ws;
  bf16*  hbf  = (bf16*)(ws);                    // 33,554,432 B  (reused as Kt)
  bf16*  xbf  = (bf16*)(ws + 33554432);         // 33,554,432 B  (reused as Vt)
  bf16*  wcat = (bf16*)(ws + 67108864);         //  6,291,456 B  [3072][1024]
  bf16*  wob  = (bf16*)(ws + 73400320);         //  2,097,152 B  [1024][1024] (contiguous after wcat)
  bf16*  qkv  = (bf16*)(ws + 75497472);         // 100,663,296 B [16384][3072]
  float* kvb  = (float*)(ws + 176160768);       //  1,048,576 B  [64][64][64]
  float* ksb  = (float*)(ws + 177209344);       //     16,384 B  [64][64]
  bf16*  op   = (bf16*)(ws + 177225728);        // 33,554,432 B  [16384][1024]

  bf16* Kt = hbf;
  bf16* Vt = xbf;

  cast_hx<<<dim3(4096), 256, 0, stream>>>(h, x, hbf);
  cast_w<<<dim3(2048), 256, 0, stream>>>(Wq, Wk, Wv, Wo, wcat);

  hipMemsetAsync(kvb, 0, 1048576 + 16384, stream);

  gemm_bt<0><<<dim3(128, 24), 256, 0, stream>>>(hbf, xbf, wcat, bq, bk, bv, qkv);
  transpose_kv<<<dim3(64, 32), 256, 0, stream>>>(qkv, Kt, Vt, ksb);
  kv_gemm<<<dim3(64, KSPLIT), 256, 0, stream>>>(Kt, Vt, kvb);
  attn_out<<<dim3(64, 32), 256, 0, stream>>>(qkv, kvb, ksb, op);
  gemm_bt<1><<<dim3(128, 8), 256, 0, stream>>>(op, nullptr, wob, bo, nullptr, nullptr, d_out);
}

// Round 7
// 283.923 us; speedup vs baseline: 1.1346x; 1.1346x over previous
//
#include <hip/hip_runtime.h>
#include <hip/hip_bf16.h>
#include <cstdint>
#include <cstddef>

#define S_LEN   4096
#define BATCHN  4
#define DMODEL  1024
#define NHEADS  16
#define HDIM    64
#define MROWS   (S_LEN*BATCHN)   // 16384
#define KDIM    1024
#define KSPLIT  8

typedef __bf16 bf16;
typedef bf16 bf16x8 __attribute__((ext_vector_type(8)));
typedef bf16 bf16x4 __attribute__((ext_vector_type(4)));
typedef float f32x4 __attribute__((ext_vector_type(4)));

#define MFMA16(a,b,c) __builtin_amdgcn_mfma_f32_16x16x32_bf16(a,b,c,0,0,0)

__device__ __forceinline__ void gll16(const void* g, void* l) {
  __builtin_amdgcn_global_load_lds((const __attribute__((address_space(1))) unsigned*)g,
                                   (__attribute__((address_space(3))) unsigned*)l,
                                   16, 0, 0);
}

// ---------------- cast fp32 [S][B][D] -> bf16 [B][S][D] for h and x ----------------
__global__ __launch_bounds__(256) void cast_perm(const float* __restrict__ h,
                                                 const float* __restrict__ x,
                                                 bf16* __restrict__ hb,
                                                 bf16* __restrict__ xb) {
  const int n = MROWS * KDIM;              // 16,777,216 elements each
  int stride = gridDim.x * blockDim.x * 4;
  for (int i = (blockIdx.x * blockDim.x + threadIdx.x) * 4; i < n; i += stride) {
    int s = i >> 12, b = (i >> 10) & 3, d = i & 1023;
    size_t o = ((size_t)(b * S_LEN + s) << 10) | d;
    float4 f = *(const float4*)(h + i);
    bf16x4 u; u[0]=(bf16)f.x; u[1]=(bf16)f.y; u[2]=(bf16)f.z; u[3]=(bf16)f.w;
    *(bf16x4*)(hb + o) = u;
    float4 g = *(const float4*)(x + i);
    bf16x4 v; v[0]=(bf16)g.x; v[1]=(bf16)g.y; v[2]=(bf16)g.z; v[3]=(bf16)g.w;
    *(bf16x4*)(xb + o) = v;
  }
}

// all four weight matrices -> contiguous wcat(3M: Wq|Wk|Wv) | wob(1M)
__global__ __launch_bounds__(256) void cast_w(const float* __restrict__ Wq,
                                              const float* __restrict__ Wk,
                                              const float* __restrict__ Wv,
                                              const float* __restrict__ Wo,
                                              bf16* __restrict__ dst) {
  const int n = 4 * 1048576;
  int stride = gridDim.x * blockDim.x * 4;
  for (int i = (blockIdx.x * blockDim.x + threadIdx.x) * 4; i < n; i += stride) {
    int r = i >> 20;
    const float* src = (r < 1) ? (Wq + i) : (r < 2) ? (Wk + i - 1048576)
                     : (r < 3) ? (Wv + i - 2097152) : (Wo + i - 3145728);
    float4 f = *(const float4*)src;
    bf16x4 o; o[0]=(bf16)f.x; o[1]=(bf16)f.y; o[2]=(bf16)f.z; o[3]=(bf16)f.w;
    *(bf16x4*)(dst + i) = o;
  }
}

// ---------------- GEMM C = A * B^T, m97 structure + XOR bank swizzle ----------------
// MODE 0 (Q):   A=hb[16384][1024], B=Wq,  C=qp bf16 [16384][1024], bias bq[col], elu+1 all.
// MODE 1 (KVT): A=Wkv[2048][1024], B=xb[16384][1024], C=kvt bf16 [2048][16384],
//               bias row-keyed (bk/bv), elu+1 iff row<1024.
// MODE 2 (OUT): A=op[16384][1024], B=Wo,  C=d_out fp32 [16384][1024], bias bo[col].
template<int MODE>
__global__ __launch_bounds__(256) void gemm_bt(
    const bf16* __restrict__ A, const bf16* __restrict__ Bw,
    const float* __restrict__ bias0, const float* __restrict__ bias1,
    void* __restrict__ Cout) {
  __shared__ __align__(16) bf16 As[128*32];
  __shared__ __align__(16) bf16 Bs[128*32];
  const int tid  = threadIdx.x;
  const int wid  = tid >> 6;
  const int lane = tid & 63;
  const int wm = wid >> 1, wn = wid & 1;
  const int mtile = blockIdx.x, ntile = blockIdx.y;
  const size_t arow0 = (size_t)mtile * 128;
  const size_t brow0 = (size_t)ntile * 128;
  const int CP = (MODE == 1) ? MROWS : DMODEL;   // C pitch
  f32x4 acc[4][4] = {};
  const int lr = lane >> 2;        // row within 16-row segment
  const int lc = lane & 3;         // 16B chunk within row
  const int ssrc = (((lc << 4) ^ (((lr >> 1) & 3) << 4)) >> 1);
  const int fhalf = (lane >> 4) << 4;

  for (int k0 = 0; k0 < KDIM; k0 += 32) {
    #pragma unroll
    for (int i = 0; i < 2; ++i) {
      int seg = (wid << 1) | i;    // 0..7
      gll16(A  + (arow0 + seg*16 + lr) * KDIM + k0 + ssrc, As + seg*512);
      gll16(Bw + (brow0 + seg*16 + lr) * KDIM + k0 + ssrc, Bs + seg*512);
    }
    __syncthreads();
    bf16x8 af[4], bfv[4];
    #pragma unroll
    for (int m = 0; m < 4; ++m) {
      int R = wm*64 + m*16 + (lane & 15);
      af[m] = *(const bf16x8*)((const char*)As + R*64 + (fhalf ^ (((R >> 1) & 3) << 4)));
    }
    #pragma unroll
    for (int n = 0; n < 4; ++n) {
      int R = wn*64 + n*16 + (lane & 15);
      bfv[n] = *(const bf16x8*)((const char*)Bs + R*64 + (fhalf ^ (((R >> 1) & 3) << 4)));
    }
    #pragma unroll
    for (int m = 0; m < 4; ++m)
      #pragma unroll
      for (int n = 0; n < 4; ++n)
        acc[m][n] = MFMA16(af[m], bfv[n], acc[m][n]);
    __syncthreads();
  }

  #pragma unroll
  for (int m = 0; m < 4; ++m) {
    int rowb = mtile*128 + wm*64 + m*16 + ((lane >> 4) << 2);
    #pragma unroll
    for (int n = 0; n < 4; ++n) {
      int col = ntile*128 + wn*64 + n*16 + (lane & 15);
      if (MODE == 0) {
        float bias = bias0[col];
        bf16* C = (bf16*)Cout;
        #pragma unroll
        for (int i = 0; i < 4; ++i) {
          float v = acc[m][n][i] + bias;
          v = (v > 0.f) ? v + 1.f : __expf(v);          // elu(x)+1
          C[(size_t)(rowb+i)*CP + col] = (bf16)v;
        }
      } else if (MODE == 1) {
        bf16* C = (bf16*)Cout;
        #pragma unroll
        for (int i = 0; i < 4; ++i) {
          int r = rowb + i;                              // global out-dim row (0..2047)
          float v = acc[m][n][i] + ((r < 1024) ? bias0[r] : bias1[r - 1024]);
          if (r < 1024) v = (v > 0.f) ? v + 1.f : __expf(v);
          C[(size_t)r*CP + col] = (bf16)v;
        }
      } else {
        float bias = bias0[col];
        float* C = (float*)Cout;
        #pragma unroll
        for (int i = 0; i < 4; ++i)
          C[(size_t)(rowb+i)*CP + col] = acc[m][n][i] + bias;
      }
    }
  }
}

// ---------------- KV[bh][d][v] = sum_s Kp[d][s]*Vp[v][s]; Ksum[bh][d] fused ------------
// kvt layout: [2048 rows d_global | 1024+V][16384 = b*4096+s]. grid (64 bh, KSPLIT).
__global__ __launch_bounds__(256) void kv_gemm(const bf16* __restrict__ kvt,
                                               float* __restrict__ KVg,
                                               float* __restrict__ Ksumg) {
  const int bh = blockIdx.x;
  const int k0base = blockIdx.y * (S_LEN / KSPLIT);
  const int b = bh >> 4, hh = bh & 15;
  const int tid = threadIdx.x, wid = tid >> 6, lane = tid & 63;
  const int wm = wid >> 1, wn = wid & 1;
  __shared__ __align__(16) bf16 Ks[64*64];
  __shared__ __align__(16) bf16 Vs[64*64];
  const bf16* Kh = kvt + (size_t)(hh*64) * MROWS + b * S_LEN;
  const bf16* Vh = kvt + (size_t)(1024 + hh*64) * MROWS + b * S_LEN;
  f32x4 acc[2][2] = {};
  float ksl0 = 0.f, ksl1 = 0.f;

  for (int k0 = k0base; k0 < k0base + S_LEN/KSPLIT; k0 += 64) {
    #pragma unroll
    for (int j = 0; j < 4; ++j) {
      int cchunk = wid*4 + j;
      int r = (cchunk & 7) * 8 + (lane >> 3);
      int colb = (lane & 7) * 16;
      int scol = colb ^ ((r & 7) << 4);
      const bf16* src = (cchunk < 8) ? Kh : Vh;
      bf16* dst = ((cchunk < 8) ? Ks : Vs) + (size_t)(cchunk & 7) * 8 * 64;
      gll16(src + (size_t)r * MROWS + k0 + (scol >> 1), dst);
    }
    __syncthreads();
    #pragma unroll
    for (int ksb = 0; ksb < 2; ++ksb) {
      bf16x8 af[2], bv[2];
      #pragma unroll
      for (int m = 0; m < 2; ++m) {
        int R = wm*32 + m*16 + (lane & 15);
        int cb = (ksb*64 + ((lane >> 4) << 4)) ^ ((R & 7) << 4);
        af[m] = *(const bf16x8*)((const char*)Ks + R*128 + cb);
      }
      #pragma unroll
      for (int n = 0; n < 2; ++n) {
        int R = wn*32 + n*16 + (lane & 15);
        int cb = (ksb*64 + ((lane >> 4) << 4)) ^ ((R & 7) << 4);
        bv[n] = *(const bf16x8*)((const char*)Vs + R*128 + cb);
      }
      if (wn == 0) {                       // Ksum partials (each Kp element once per block)
        #pragma unroll
        for (int j = 0; j < 8; ++j) { ksl0 += (float)af[0][j]; ksl1 += (float)af[1][j]; }
      }
      #pragma unroll
      for (int m = 0; m < 2; ++m)
        #pragma unroll
        for (int n = 0; n < 2; ++n)
          acc[m][n] = MFMA16(af[m], bv[n], acc[m][n]);
    }
    __syncthreads();
  }

  #pragma unroll
  for (int m = 0; m < 2; ++m)
    #pragma unroll
    for (int n = 0; n < 2; ++n)
      #pragma unroll
      for (int i = 0; i < 4; ++i) {
        int dd = wm*32 + m*16 + ((lane >> 4) << 2) + i;
        int vv = wn*32 + n*16 + (lane & 15);
        atomicAdd(&KVg[(size_t)bh*4096 + dd*64 + vv], acc[m][n][i]);
      }

  if (wn == 0) {
    float v0 = ksl0, v1 = ksl1;
    v0 += __shfl_xor(v0, 16); v0 += __shfl_xor(v0, 32);
    v1 += __shfl_xor(v1, 16); v1 += __shfl_xor(v1, 32);
    if (lane < 16) {
      atomicAdd(&Ksumg[bh*64 + wm*32 + lane], v0);
      atomicAdd(&Ksumg[bh*64 + wm*32 + 16 + lane], v1);
    }
  }
}

// ---------------- out_pre = (Qp @ KV) / Z ----------------
// qp rows are b*4096+s; op rows written back in s*4+b order.
__global__ __launch_bounds__(256) void attn_out(const bf16* __restrict__ QP,
                                                const float* __restrict__ KVg,
                                                const float* __restrict__ Ksumg,
                                                bf16* __restrict__ OP) {
  const int head = blockIdx.x, stile = blockIdx.y;
  const int b = head >> 4, hh = head & 15;
  const int tid = threadIdx.x;
  const int wid = tid >> 6, lane = tid & 63;
  const int s0 = stile * 128;
  __shared__ __align__(16) bf16 Qs[128*64];
  __shared__ __align__(16) bf16 KVt[64*64];
  __shared__ float ksum_s[64];
  __shared__ float rZ[128];

  const float* KVh = KVg + (size_t)head*4096;
  #pragma unroll
  for (int i = 0; i < 16; ++i) {
    int idx = i*256 + tid;
    int dd = idx >> 6, vv = idx & 63;
    KVt[vv*64 + dd] = (bf16)KVh[idx];
  }
  if (tid < 64) ksum_s[tid] = Ksumg[head*64 + tid];
  #pragma unroll
  for (int p = 0; p < 4; ++p) {
    int row = p*32 + wid*8 + (lane >> 3);
    gll16(QP + ((size_t)(b*S_LEN + s0 + row))*DMODEL + hh*64 + ((lane&7)<<3),
          Qs + (p*32 + wid*8)*64);
  }
  __syncthreads();

  if (tid < 128) {
    float z = 0.f;
    #pragma unroll
    for (int dd = 0; dd < 64; ++dd) z += (float)Qs[tid*64 + dd] * ksum_s[dd];
    rZ[tid] = 1.f / (z + 1e-6f);
  }
  __syncthreads();

  f32x4 acc[2][4] = {};
  #pragma unroll
  for (int ksb = 0; ksb < 2; ++ksb) {
    bf16x8 af[2], bv[4];
    #pragma unroll
    for (int m = 0; m < 2; ++m)
      af[m] = *(const bf16x8*)(Qs + (wid*32 + m*16 + (lane & 15))*64 + ksb*32 + ((lane>>4)<<3));
    #pragma unroll
    for (int n = 0; n < 4; ++n)
      bv[n] = *(const bf16x8*)(KVt + (n*16 + (lane & 15))*64 + ksb*32 + ((lane>>4)<<3));
    #pragma unroll
    for (int m = 0; m < 2; ++m)
      #pragma unroll
      for (int n = 0; n < 4; ++n)
        acc[m][n] = MFMA16(af[m], bv[n], acc[m][n]);
  }

  #pragma unroll
  for (int m = 0; m < 2; ++m)
    #pragma unroll
    for (int n = 0; n < 4; ++n)
      #pragma unroll
      for (int i = 0; i < 4; ++i) {
        int row = wid*32 + m*16 + ((lane >> 4) << 2) + i;
        int vv  = n*16 + (lane & 15);
        float val = acc[m][n][i] * rZ[row];
        OP[((size_t)((s0+row)*BATCHN + b))*DMODEL + hh*64 + vv] = (bf16)val;
      }
}

// ---------------- launch ----------------
extern "C" void kernel_launch(void* const* d_in, const int* in_sizes, int n_in,
                              void* d_out, int out_size, void* d_ws, size_t ws_size,
                              hipStream_t stream) {
  const float* h  = (const float*)d_in[0];
  const float* x  = (const float*)d_in[1];
  const float* Wq = (const float*)d_in[2];
  const float* bq = (const float*)d_in[3];
  const float* Wk = (const float*)d_in[4];
  const float* bk = (const float*)d_in[5];
  const float* Wv = (const float*)d_in[6];
  const float* bv = (const float*)d_in[7];
  const float* Wo = (const float*)d_in[8];
  const float* bo = (const float*)d_in[9];

  char* ws = (char*)d_ws;
  bf16*  hb   = (bf16*)(ws);                    // 33,554,432 B  [B][S][D]
  bf16*  xb   = (bf16*)(ws + 33554432);         // 33,554,432 B  [B][S][D]
  bf16*  wcat = (bf16*)(ws + 67108864);         //  6,291,456 B  Wq|Wk|Wv [3072][1024]
  bf16*  wob  = (bf16*)(ws + 73400320);         //  2,097,152 B  [1024][1024]
  bf16*  qp   = (bf16*)(ws + 75497472);         // 33,554,432 B  [16384 b*s][1024]
  bf16*  kvt  = (bf16*)(ws + 109051904);        // 67,108,864 B  [2048][16384 b*s]
  float* kvb  = (float*)(ws + 176160768);       //  1,048,576 B  [64][64][64]
  float* ksb  = (float*)(ws + 177209344);       //     16,384 B  [64][64]
  bf16*  op   = (bf16*)(ws + 177225728);        // 33,554,432 B  [16384 s*b][1024]
  // total 210,780,160 B

  cast_perm<<<dim3(4096), 256, 0, stream>>>(h, x, hb, xb);
  cast_w<<<dim3(2048), 256, 0, stream>>>(Wq, Wk, Wv, Wo, wcat);

  hipMemsetAsync(kvb, 0, 1048576 + 16384, stream);

  gemm_bt<1><<<dim3(16, 128), 256, 0, stream>>>(wcat + 1048576, xb, bk, bv, kvt);
  gemm_bt<0><<<dim3(128, 8),  256, 0, stream>>>(hb, wcat, bq, nullptr, qp);
  kv_gemm<<<dim3(64, KSPLIT), 256, 0, stream>>>(kvt, kvb, ksb);
  attn_out<<<dim3(64, 32), 256, 0, stream>>>(qp, kvb, ksb, op);
  gemm_bt<2><<<dim3(128, 8), 256, 0, stream>>>(op, wob, bo, nullptr, d_out);
}